// Round 14
// baseline (88.508 us; speedup 1.0000x reference)
//
#include <hip/hip_runtime.h>

#define NDIR  6
#define B_    16
#define N_IN  16384
#define N_OUT 8192
#define IDIM  128
#define ODIM  128
#define TOTAL (B_ * N_OUT)   // 131072 nodes
#define BM    64             // nodes per block (4 waves x 16 rows)
#define MAXBLK (TOTAL / BM + NDIR)   // 2054

// d_ws layout (ints): [0..7]=cnt, [8..14]=node offsets, [16..23]=cursors,
// [24..30]=block offsets, ids at int 64, Wt (bf16 hi/lo swizzled) at 131584.
#define WS_CNT 0
#define WS_OFF 8
#define WS_CUR 16
#define WS_BLK 24
#define WS_IDS 64
#define WS_WT  131584

using s16x8 = __attribute__((ext_vector_type(8))) short;   // 8 bf16 (4 VGPR)
using f32x4 = __attribute__((ext_vector_type(4))) float;   // acc frag

__global__ void zero_kernel(int* ws) {
    int t = threadIdx.x;
    if (t < 32) ws[t] = 0;
}

__global__ void count_kernel(const int* __restrict__ vec, const int* __restrict__ dmap,
                             int* __restrict__ ws) {
    __shared__ int h[NDIR];
    int t = threadIdx.x;
    if (t < NDIR) h[t] = 0;
    __syncthreads();
    int id = blockIdx.x * 256 + t;
    if (id < TOTAL) {
        int d = dmap[vec[id]];
        atomicAdd(&h[d], 1);
    }
    __syncthreads();
    if (t < NDIR && h[t]) atomicAdd(&ws[WS_CNT + t], h[t]);
}

__global__ void prefix_kernel(int* ws) {
    if (threadIdx.x == 0) {
        int acc = 0, bacc = 0;
        for (int i = 0; i < NDIR; ++i) {
            ws[WS_OFF + i] = acc;
            ws[WS_CUR + i] = acc;
            ws[WS_BLK + i] = bacc;
            int c = ws[WS_CNT + i];
            acc += c;
            bacc += (c + BM - 1) / BM;
        }
        ws[WS_OFF + NDIR] = acc;
        ws[WS_BLK + NDIR] = bacc;
    }
}

__global__ void scatter_kernel(const int* __restrict__ vec, const int* __restrict__ dmap,
                               int* __restrict__ ws) {
    __shared__ int h[NDIR];
    __shared__ int base[NDIR];
    int t = threadIdx.x;
    if (t < NDIR) h[t] = 0;
    __syncthreads();
    int id = blockIdx.x * 256 + t;
    int d = 0, pos = 0;
    if (id < TOTAL) {
        d = dmap[vec[id]];
        pos = atomicAdd(&h[d], 1);
    }
    __syncthreads();
    if (t < NDIR) base[t] = h[t] ? atomicAdd(&ws[WS_CUR + t], h[t]) : 0;
    __syncthreads();
    if (id < TOTAL) ws[WS_IDS + base[d] + pos] = id;
}

// Pre-transpose + bf16-split + swizzle W into d_ws (R7 layout; 0 conflicts).
// Per (dir d, kstep s): 16KB = hi[col][chunk'][i] (8KB) then lo (8KB);
// stored chunk c' holds source chunk c'^key, key(col) = (col>>1)&3.
__global__ void wconvert_kernel(const float* __restrict__ W, int* __restrict__ ws) {
    unsigned short* wt = (unsigned short*)(ws + WS_WT);
    int g = blockIdx.x * 256 + threadIdx.x;      // 0..196607
    int dsb = g >> 12;                           // d*8+s, 0..47
    int e = g & 4095;
    int col = e >> 5;
    int kk = e & 31;
    int cp = kk >> 3, i = kk & 7;
    int key = (col >> 1) & 3;
    int d = dsb >> 3, s = dsb & 7;
    int ksrc = s * 32 + ((cp ^ key) << 3) + i;
    float w = W[((d * 256) + ksrc) * 128 + col];
    unsigned u = __float_as_uint(w);
    float hf = __uint_as_float(u & 0xFFFF0000u);
    float lf = w - hf;
    int base = dsb * 8192 + col * 32 + cp * 8 + i;
    wt[base] = (unsigned short)(u >> 16);
    wt[base + 4096] = (unsigned short)(__float_as_uint(lf) >> 16);
}

__device__ __forceinline__ void cvt8(float4 a, float4 b, s16x8& h, s16x8& lo) {
    float x[8] = {a.x, a.y, a.z, a.w, b.x, b.y, b.z, b.w};
    #pragma unroll
    for (int j = 0; j < 8; ++j) {
        unsigned u = __float_as_uint(x[j]);
        float hf = __uint_as_float(u & 0xFFFF0000u);
        float lf = x[j] - hf;
        h[j] = (short)(u >> 16);
        lo[j] = (short)(__float_as_uint(lf) >> 16);
    }
}

#define CFENCE() asm volatile("" ::: "memory")

// MFMA gather-GEMM, burst-gather version: block = 64 nodes x 128 outputs,
// 4 waves of one 16x128 tile. K=256 in 8 steps of 32; fp32 via 3x bf16 MFMA.
// A-gather: each child row's FULL 512B fetched in one 8x dwordx4 burst
// (per lane: its 4 chunks of one row-half = 32 floats in regs) -> DRAM sees
// whole-row bursts instead of time-scattered 128B requests.
// In-order vmcnt schedule (S=4 insts, R=8 insts):
//   prologue: S0,R0(12) | s0: +S1, wait 4 (S0+R0), issue R1
//   s1: +S2, wait 12 (S1) | s2: +S3, wait 4 (R1+S2) | s3-6: wait 4 | s7: wait 0
__global__ __launch_bounds__(256, 3) void gemm_kernel(
    const float* __restrict__ last, const float* __restrict__ bias,
    const float* __restrict__ alphap,
    const int* __restrict__ vec, const int* __restrict__ drev,
    const int* __restrict__ child_l, const int* __restrict__ child_r,
    const int* __restrict__ ws, float* __restrict__ out)
{
    int i = blockIdx.x;
    if (i >= ws[WS_BLK + NDIR]) return;
    int dir = 0;
    #pragma unroll
    for (int d = 1; d < NDIR; ++d)
        if (i >= ws[WS_BLK + d]) dir = d;
    int tile = i - ws[WS_BLK + dir];
    int start = ws[WS_OFF + dir];
    int end   = ws[WS_OFF + dir + 1];
    int m0 = start + tile * BM;
    const int* ids = ws + WS_IDS;

    __shared__ unsigned short wbuf[2][8192];   // 2 x 16KB W tiles
    __shared__ int s_row0[BM], s_row1[BM], s_oid[BM];

    int t = threadIdx.x;
    int l = t & 63;
    int wid = t >> 6;

    if (t < BM) {
        int idx = m0 + t;
        bool valid = idx < end;
        int id = ids[valid ? idx : end - 1];
        int b = id >> 13;            // N_OUT = 8192
        int n = id & (N_OUT - 1);
        int v = vec[id];
        int r = drev[v];
        int cl = child_l[n];
        int cr = child_r[n];
        int first  = r ? cr : cl;
        int second = r ? cl : cr;
        s_row0[t] = b * N_IN + first;
        s_row1[t] = b * N_IN + second;
        s_oid[t]  = valid ? id : -1;
    }
    __syncthreads();   // once, before the pipeline starts

    // this wave's rows (16 rows; 4 lanes per row via l>>4 chunk split)
    int m = wid * 16 + (l & 15);
    int rowA[2] = { s_row0[m], s_row1[m] };

    const char* wt_blk = (const char*)(ws + WS_WT) + (size_t)dir * 8 * 16384;

    #define STAGE_W(buf, s_)                                                     \
        {                                                                        \
            const char* gsrc = wt_blk + (size_t)(s_) * 16384 + wid * 4096 + l * 16; \
            char* ldst = (char*)&wbuf[buf][0] + wid * 4096;                      \
            _Pragma("unroll")                                                    \
            for (int i_ = 0; i_ < 4; ++i_) {                                     \
                __builtin_amdgcn_global_load_lds(                                \
                    (const __attribute__((address_space(1))) void*)(gsrc + i_ * 1024), \
                    (__attribute__((address_space(3))) void*)(ldst + i_ * 1024), \
                    16, 0, 0);                                                   \
            }                                                                    \
        }

    // full-row burst: 8 x dwordx4 covering this lane's 32 floats (4 chunks)
    #define ISSUE_R(arr, h_)                                                     \
        {                                                                        \
            const float* rbase = last + (size_t)rowA[h_] * IDIM + (l >> 4) * 8;  \
            _Pragma("unroll")                                                    \
            for (int c_ = 0; c_ < 4; ++c_) {                                     \
                arr[c_ * 2]     = *(const float4*)(rbase + c_ * 32);             \
                arr[c_ * 2 + 1] = *(const float4*)(rbase + c_ * 32 + 4);         \
            }                                                                    \
        }

    f32x4 acc[8];
    #pragma unroll
    for (int nf = 0; nf < 8; ++nf)
        acc[nf] = (f32x4){0.f, 0.f, 0.f, 0.f};

    float4 xaA[8], xaB[8];   // full row-half A data (static indices)

    // prologue: queue = [S0(4), R0(8)]
    STAGE_W(0, 0);
    CFENCE();
    ISSUE_R(xaA, 0);
    CFENCE();

    #pragma unroll
    for (int s = 0; s < 8; ++s) {
        int cur = s & 1;
        // --- issue STAGE_{s+1}
        if (s < 7) { STAGE_W(cur ^ 1, s + 1); CFENCE(); }
        // --- counted wait (in-order drain; see schedule above)
        if (s == 1)      { asm volatile("s_waitcnt vmcnt(12)" ::: "memory"); }
        else if (s == 7) { asm volatile("s_waitcnt vmcnt(0)"  ::: "memory"); }
        else             { asm volatile("s_waitcnt vmcnt(4)"  ::: "memory"); }
        __builtin_amdgcn_s_barrier();   // buf[cur] staged by ALL waves
        CFENCE();
        // --- consume A chunk s&3 of the current row-half (in regs)
        s16x8 ah, al;
        if (s < 4) cvt8(xaA[(s & 3) * 2], xaA[(s & 3) * 2 + 1], ah, al);
        else       cvt8(xaB[(s & 3) * 2], xaB[(s & 3) * 2 + 1], ah, al);
        // --- issue row1 burst right after row0's data is certified (iter 0)
        if (s == 0) { CFENCE(); ISSUE_R(xaB, 1); CFENCE(); }
        // --- B frags in quarters + 3-term split MFMA (24 MFMA/step)
        #pragma unroll
        for (int q = 0; q < 4; ++q) {
            s16x8 bh[2], bl[2];
            #pragma unroll
            for (int i2 = 0; i2 < 2; ++i2) {
                int nf = q * 2 + i2;
                int col = nf * 16 + (l & 15);
                int cp = (l >> 4) ^ ((col >> 1) & 3);
                int off = col * 32 + cp * 8;          // shorts
                bh[i2] = *(const s16x8*)&wbuf[cur][off];
                bl[i2] = *(const s16x8*)&wbuf[cur][off + 4096];
            }
            #pragma unroll
            for (int i2 = 0; i2 < 2; ++i2) {
                int nf = q * 2 + i2;
                acc[nf] = __builtin_amdgcn_mfma_f32_16x16x32_bf16(ah, bh[i2], acc[nf], 0, 0, 0);
                acc[nf] = __builtin_amdgcn_mfma_f32_16x16x32_bf16(ah, bl[i2], acc[nf], 0, 0, 0);
                acc[nf] = __builtin_amdgcn_mfma_f32_16x16x32_bf16(al, bh[i2], acc[nf], 0, 0, 0);
            }
        }
        // --- all waves done reading buf[cur]; next iter may stage into it
        if (s < 7) {
            CFENCE();
            __builtin_amdgcn_s_barrier();
            CFENCE();
        }
    }

    // --- epilogue: D frag row=(l>>4)*4+j, col=l&15 (m89/m91 verified)
    float alpha = alphap[0];
    #pragma unroll
    for (int nf = 0; nf < 8; ++nf) {
        int col = nf * 16 + (l & 15);
        float bv = bias[dir * ODIM + col];
        #pragma unroll
        for (int j = 0; j < 4; ++j) {
            int mloc = wid * 16 + (l >> 4) * 4 + j;
            int id = s_oid[mloc];
            if (id < 0) continue;
            float y = acc[nf][j] + bv;
            out[(size_t)id * ODIM + col] = y >= 0.f ? y : alpha * y;
        }
    }
    #undef STAGE_W
    #undef ISSUE_R
}

extern "C" void kernel_launch(void* const* d_in, const int* in_sizes, int n_in,
                              void* d_out, int out_size, void* d_ws, size_t ws_size,
                              hipStream_t stream) {
    const float* last    = (const float*)d_in[0];
    const float* W       = (const float*)d_in[1];
    const float* bias    = (const float*)d_in[2];
    const float* alpha   = (const float*)d_in[3];
    const int*   vec     = (const int*)d_in[4];
    const int*   dmap    = (const int*)d_in[5];
    const int*   drev    = (const int*)d_in[6];
    const int*   child_l = (const int*)d_in[7];
    const int*   child_r = (const int*)d_in[8];
    float* out = (float*)d_out;
    int*   ws  = (int*)d_ws;

    zero_kernel<<<1, 64, 0, stream>>>(ws);
    count_kernel<<<TOTAL / 256, 256, 0, stream>>>(vec, dmap, ws);
    prefix_kernel<<<1, 64, 0, stream>>>(ws);
    scatter_kernel<<<TOTAL / 256, 256, 0, stream>>>(vec, dmap, ws);
    wconvert_kernel<<<(NDIR * 8 * 4096) / 256, 256, 0, stream>>>(W, ws);
    gemm_kernel<<<MAXBLK, 256, 0, stream>>>(last, bias, alpha, vec, drev,
                                            child_l, child_r, ws, out);
}

// Round 16
// 83.874 us; speedup vs baseline: 1.0553x; 1.0553x over previous
//
#include <hip/hip_runtime.h>

#define NDIR  6
#define B_    16
#define N_IN  16384
#define N_OUT 8192
#define IDIM  128
#define ODIM  128
#define TOTAL (B_ * N_OUT)   // 131072 nodes
#define BM    64             // nodes per block (4 waves x 16 rows)
#define MAXBLK (TOTAL / BM + NDIR)   // 2054
#define NBUCKET 128          // row0 buckets (>>11 of b*N_IN+first, 1MB span)
#define NKEY (NDIR * NBUCKET)

// d_ws layout (ints): [8..14]=per-dir node offsets, [24..30]=per-dir block
// offsets, [64..831]=bucket counters, [2048..2815]=bucket cursors,
// ids at 4096, Wt (bf16 hi/lo swizzled) at 135168.
#define WS_OFF  8
#define WS_BLK  24
#define WS_CNT2 64
#define WS_CURS 2048
#define WS_IDS  4096
#define WS_WT   135168

using s16x8 = __attribute__((ext_vector_type(8))) short;   // 8 bf16 (4 VGPR)
using f32x4 = __attribute__((ext_vector_type(4))) float;   // acc frag

__device__ __forceinline__ int node_key(const int* vec, const int* dmap,
                                        const int* drev, const int* child_l,
                                        const int* child_r, int id, int* dirOut) {
    int v = vec[id];
    int d = dmap[v];
    int r = drev[v];
    int n = id & (N_OUT - 1);
    int b = id >> 13;
    int first = r ? child_r[n] : child_l[n];
    *dirOut = d;
    return d * NBUCKET + ((b * N_IN + first) >> 11);
}

__global__ void zero_kernel(int* ws) {
    int t = threadIdx.x;
    for (int k = t; k < NKEY; k += 256) ws[WS_CNT2 + k] = 0;
}

__global__ void count_kernel(const int* __restrict__ vec, const int* __restrict__ dmap,
                             const int* __restrict__ drev, const int* __restrict__ child_l,
                             const int* __restrict__ child_r, int* __restrict__ ws) {
    __shared__ int h[NKEY];
    int t = threadIdx.x;
    for (int k = t; k < NKEY; k += 256) h[k] = 0;
    __syncthreads();
    int id = blockIdx.x * 256 + t;
    int dir;
    int key = node_key(vec, dmap, drev, child_l, child_r, id, &dir);
    atomicAdd(&h[key], 1);
    __syncthreads();
    for (int k = t; k < NKEY; k += 256)
        if (h[k]) atomicAdd(&ws[WS_CNT2 + k], h[k]);
}

// 1 block x 256: exclusive-scan 768 counters (3/thread) -> cursors,
// then per-dir node offsets + block offsets.
__global__ void prefix_kernel(int* ws) {
    __shared__ int part[256];
    __shared__ int ex[256];
    int t = threadIdx.x;
    int c[3], s = 0;
    #pragma unroll
    for (int j = 0; j < 3; ++j) { c[j] = ws[WS_CNT2 + t * 3 + j]; s += c[j]; }
    part[t] = s;
    __syncthreads();
    if (t == 0) {
        int a = 0;
        for (int i = 0; i < 256; ++i) { ex[i] = a; a += part[i]; }
    }
    __syncthreads();
    int a = ex[t];
    #pragma unroll
    for (int j = 0; j < 3; ++j) { ws[WS_CURS + t * 3 + j] = a; a += c[j]; }
    __threadfence();
    __syncthreads();
    if (t == 0) {
        for (int d = 0; d < NDIR; ++d) ws[WS_OFF + d] = ws[WS_CURS + d * NBUCKET];
        ws[WS_OFF + NDIR] = TOTAL;
        int bacc = 0;
        for (int d = 0; d < NDIR; ++d) {
            ws[WS_BLK + d] = bacc;
            int cnt = ws[WS_OFF + d + 1] - ws[WS_OFF + d];
            bacc += (cnt + BM - 1) / BM;
        }
        ws[WS_BLK + NDIR] = bacc;
    }
}

__global__ void scatter_kernel(const int* __restrict__ vec, const int* __restrict__ dmap,
                               const int* __restrict__ drev, const int* __restrict__ child_l,
                               const int* __restrict__ child_r, int* __restrict__ ws) {
    __shared__ int h[NKEY];
    __shared__ int base[NKEY];
    int t = threadIdx.x;
    for (int k = t; k < NKEY; k += 256) h[k] = 0;
    __syncthreads();
    int id = blockIdx.x * 256 + t;
    int dir;
    int key = node_key(vec, dmap, drev, child_l, child_r, id, &dir);
    int pos = atomicAdd(&h[key], 1);
    __syncthreads();
    for (int k = t; k < NKEY; k += 256)
        base[k] = h[k] ? atomicAdd(&ws[WS_CURS + k], h[k]) : 0;
    __syncthreads();
    ws[WS_IDS + base[key] + pos] = id;
}

// Pre-transpose + bf16-split + swizzle W into d_ws (R7 layout; 0 conflicts).
__global__ void wconvert_kernel(const float* __restrict__ W, int* __restrict__ ws) {
    unsigned short* wt = (unsigned short*)(ws + WS_WT);
    int g = blockIdx.x * 256 + threadIdx.x;      // 0..196607
    int dsb = g >> 12;                           // d*8+s, 0..47
    int e = g & 4095;
    int col = e >> 5;
    int kk = e & 31;
    int cp = kk >> 3, i = kk & 7;
    int key = (col >> 1) & 3;
    int d = dsb >> 3, s = dsb & 7;
    int ksrc = s * 32 + ((cp ^ key) << 3) + i;
    float w = W[((d * 256) + ksrc) * 128 + col];
    unsigned u = __float_as_uint(w);
    float hf = __uint_as_float(u & 0xFFFF0000u);
    float lf = w - hf;
    int base = dsb * 8192 + col * 32 + cp * 8 + i;
    wt[base] = (unsigned short)(u >> 16);
    wt[base + 4096] = (unsigned short)(__float_as_uint(lf) >> 16);
}

__device__ __forceinline__ void cvt8(float4 a, float4 b, s16x8& h, s16x8& lo) {
    float x[8] = {a.x, a.y, a.z, a.w, b.x, b.y, b.z, b.w};
    #pragma unroll
    for (int j = 0; j < 8; ++j) {
        unsigned u = __float_as_uint(x[j]);
        float hf = __uint_as_float(u & 0xFFFF0000u);
        float lf = x[j] - hf;
        h[j] = (short)(u >> 16);
        lo[j] = (short)(__float_as_uint(lf) >> 16);
    }
}

#define CFENCE() asm volatile("" ::: "memory")

// MFMA gather-GEMM (identical to R14 except ws offsets): block = 64 nodes x
// 128 outputs, 4 waves of one 16x128 tile. fp32 via 3x bf16 MFMA. Whole-row
// burst A-gather; counted-vmcnt W pipeline. Nodes now sorted by (dir,
// row0-bucket) -> first-child gathers are L2-local and near-sorted.
__global__ __launch_bounds__(256, 3) void gemm_kernel(
    const float* __restrict__ last, const float* __restrict__ bias,
    const float* __restrict__ alphap,
    const int* __restrict__ vec, const int* __restrict__ drev,
    const int* __restrict__ child_l, const int* __restrict__ child_r,
    const int* __restrict__ ws, float* __restrict__ out)
{
    int i = blockIdx.x;
    if (i >= ws[WS_BLK + NDIR]) return;
    int dir = 0;
    #pragma unroll
    for (int d = 1; d < NDIR; ++d)
        if (i >= ws[WS_BLK + d]) dir = d;
    int tile = i - ws[WS_BLK + dir];
    int start = ws[WS_OFF + dir];
    int end   = ws[WS_OFF + dir + 1];
    int m0 = start + tile * BM;
    const int* ids = ws + WS_IDS;

    __shared__ unsigned short wbuf[2][8192];   // 2 x 16KB W tiles
    __shared__ int s_row0[BM], s_row1[BM], s_oid[BM];

    int t = threadIdx.x;
    int l = t & 63;
    int wid = t >> 6;

    if (t < BM) {
        int idx = m0 + t;
        bool valid = idx < end;
        int id = ids[valid ? idx : end - 1];
        int b = id >> 13;            // N_OUT = 8192
        int n = id & (N_OUT - 1);
        int v = vec[id];
        int r = drev[v];
        int cl = child_l[n];
        int cr = child_r[n];
        int first  = r ? cr : cl;
        int second = r ? cl : cr;
        s_row0[t] = b * N_IN + first;
        s_row1[t] = b * N_IN + second;
        s_oid[t]  = valid ? id : -1;
    }
    __syncthreads();   // once, before the pipeline starts

    // this wave's rows (16 rows; 4 lanes per row via l>>4 chunk split)
    int m = wid * 16 + (l & 15);
    int rowA[2] = { s_row0[m], s_row1[m] };

    const char* wt_blk = (const char*)(ws + WS_WT) + (size_t)dir * 8 * 16384;

    #define STAGE_W(buf, s_)                                                     \
        {                                                                        \
            const char* gsrc = wt_blk + (size_t)(s_) * 16384 + wid * 4096 + l * 16; \
            char* ldst = (char*)&wbuf[buf][0] + wid * 4096;                      \
            _Pragma("unroll")                                                    \
            for (int i_ = 0; i_ < 4; ++i_) {                                     \
                __builtin_amdgcn_global_load_lds(                                \
                    (const __attribute__((address_space(1))) void*)(gsrc + i_ * 1024), \
                    (__attribute__((address_space(3))) void*)(ldst + i_ * 1024), \
                    16, 0, 0);                                                   \
            }                                                                    \
        }

    // full-row burst: 8 x dwordx4 covering this lane's 32 floats (4 chunks)
    #define ISSUE_R(arr, h_)                                                     \
        {                                                                        \
            const float* rbase = last + (size_t)rowA[h_] * IDIM + (l >> 4) * 8;  \
            _Pragma("unroll")                                                    \
            for (int c_ = 0; c_ < 4; ++c_) {                                     \
                arr[c_ * 2]     = *(const float4*)(rbase + c_ * 32);             \
                arr[c_ * 2 + 1] = *(const float4*)(rbase + c_ * 32 + 4);         \
            }                                                                    \
        }

    f32x4 acc[8];
    #pragma unroll
    for (int nf = 0; nf < 8; ++nf)
        acc[nf] = (f32x4){0.f, 0.f, 0.f, 0.f};

    float4 xaA[8], xaB[8];   // full row-half A data (static indices)

    // prologue: queue = [S0(4), R0(8)]
    STAGE_W(0, 0);
    CFENCE();
    ISSUE_R(xaA, 0);
    CFENCE();

    #pragma unroll
    for (int s = 0; s < 8; ++s) {
        int cur = s & 1;
        // --- issue STAGE_{s+1}
        if (s < 7) { STAGE_W(cur ^ 1, s + 1); CFENCE(); }
        // --- counted wait (in-order drain)
        if (s == 1)      { asm volatile("s_waitcnt vmcnt(12)" ::: "memory"); }
        else if (s == 7) { asm volatile("s_waitcnt vmcnt(0)"  ::: "memory"); }
        else             { asm volatile("s_waitcnt vmcnt(4)"  ::: "memory"); }
        __builtin_amdgcn_s_barrier();   // buf[cur] staged by ALL waves
        CFENCE();
        // --- consume A chunk s&3 of the current row-half (in regs)
        s16x8 ah, al;
        if (s < 4) cvt8(xaA[(s & 3) * 2], xaA[(s & 3) * 2 + 1], ah, al);
        else       cvt8(xaB[(s & 3) * 2], xaB[(s & 3) * 2 + 1], ah, al);
        // --- issue row1 burst right after row0's data is certified (iter 0)
        if (s == 0) { CFENCE(); ISSUE_R(xaB, 1); CFENCE(); }
        // --- B frags in quarters + 3-term split MFMA (24 MFMA/step)
        #pragma unroll
        for (int q = 0; q < 4; ++q) {
            s16x8 bh[2], bl[2];
            #pragma unroll
            for (int i2 = 0; i2 < 2; ++i2) {
                int nf = q * 2 + i2;
                int col = nf * 16 + (l & 15);
                int cp = (l >> 4) ^ ((col >> 1) & 3);
                int off = col * 32 + cp * 8;          // shorts
                bh[i2] = *(const s16x8*)&wbuf[cur][off];
                bl[i2] = *(const s16x8*)&wbuf[cur][off + 4096];
            }
            #pragma unroll
            for (int i2 = 0; i2 < 2; ++i2) {
                int nf = q * 2 + i2;
                acc[nf] = __builtin_amdgcn_mfma_f32_16x16x32_bf16(ah, bh[i2], acc[nf], 0, 0, 0);
                acc[nf] = __builtin_amdgcn_mfma_f32_16x16x32_bf16(ah, bl[i2], acc[nf], 0, 0, 0);
                acc[nf] = __builtin_amdgcn_mfma_f32_16x16x32_bf16(al, bh[i2], acc[nf], 0, 0, 0);
            }
        }
        // --- all waves done reading buf[cur]; next iter may stage into it
        if (s < 7) {
            CFENCE();
            __builtin_amdgcn_s_barrier();
            CFENCE();
        }
    }

    // --- epilogue: D frag row=(l>>4)*4+j, col=l&15 (m89/m91 verified)
    float alpha = alphap[0];
    #pragma unroll
    for (int nf = 0; nf < 8; ++nf) {
        int col = nf * 16 + (l & 15);
        float bv = bias[dir * ODIM + col];
        #pragma unroll
        for (int j = 0; j < 4; ++j) {
            int mloc = wid * 16 + (l >> 4) * 4 + j;
            int id = s_oid[mloc];
            if (id < 0) continue;
            float y = acc[nf][j] + bv;
            out[(size_t)id * ODIM + col] = y >= 0.f ? y : alpha * y;
        }
    }
    #undef STAGE_W
    #undef ISSUE_R
}

extern "C" void kernel_launch(void* const* d_in, const int* in_sizes, int n_in,
                              void* d_out, int out_size, void* d_ws, size_t ws_size,
                              hipStream_t stream) {
    const float* last    = (const float*)d_in[0];
    const float* W       = (const float*)d_in[1];
    const float* bias    = (const float*)d_in[2];
    const float* alpha   = (const float*)d_in[3];
    const int*   vec     = (const int*)d_in[4];
    const int*   dmap    = (const int*)d_in[5];
    const int*   drev    = (const int*)d_in[6];
    const int*   child_l = (const int*)d_in[7];
    const int*   child_r = (const int*)d_in[8];
    float* out = (float*)d_out;
    int*   ws  = (int*)d_ws;

    zero_kernel<<<1, 256, 0, stream>>>(ws);
    count_kernel<<<TOTAL / 256, 256, 0, stream>>>(vec, dmap, drev, child_l, child_r, ws);
    prefix_kernel<<<1, 256, 0, stream>>>(ws);
    scatter_kernel<<<TOTAL / 256, 256, 0, stream>>>(vec, dmap, drev, child_l, child_r, ws);
    wconvert_kernel<<<(NDIR * 8 * 4096) / 256, 256, 0, stream>>>(W, ws);
    gemm_kernel<<<MAXBLK, 256, 0, stream>>>(last, bias, alpha, vec, drev,
                                            child_l, child_r, ws, out);
}

// Round 17
// 81.910 us; speedup vs baseline: 1.0806x; 1.0240x over previous
//
#include <hip/hip_runtime.h>

#define NDIR  6
#define B_    16
#define N_IN  16384
#define N_OUT 8192
#define IDIM  128
#define ODIM  128
#define TOTAL (B_ * N_OUT)   // 131072 nodes
#define BM    128            // nodes per block (4 waves x 32 rows)
#define MAXBLK (TOTAL / BM + NDIR)   // 1030

// d_ws layout (ints): [0..7]=cnt, [8..14]=node offsets, [16..23]=cursors,
// [24..30]=block offsets, ids at int 64, Wt (bf16 hi/lo swizzled) at 131584.
#define WS_CNT 0
#define WS_OFF 8
#define WS_CUR 16
#define WS_BLK 24
#define WS_IDS 64
#define WS_WT  131584

using s16x8 = __attribute__((ext_vector_type(8))) short;   // 8 bf16 (4 VGPR)
using f32x4 = __attribute__((ext_vector_type(4))) float;   // acc frag

__global__ void zero_kernel(int* ws) {
    int t = threadIdx.x;
    if (t < 32) ws[t] = 0;
}

__global__ void count_kernel(const int* __restrict__ vec, const int* __restrict__ dmap,
                             int* __restrict__ ws) {
    __shared__ int h[NDIR];
    int t = threadIdx.x;
    if (t < NDIR) h[t] = 0;
    __syncthreads();
    int id = blockIdx.x * 256 + t;
    if (id < TOTAL) {
        int d = dmap[vec[id]];
        atomicAdd(&h[d], 1);
    }
    __syncthreads();
    if (t < NDIR && h[t]) atomicAdd(&ws[WS_CNT + t], h[t]);
}

__global__ void prefix_kernel(int* ws) {
    if (threadIdx.x == 0) {
        int acc = 0, bacc = 0;
        for (int i = 0; i < NDIR; ++i) {
            ws[WS_OFF + i] = acc;
            ws[WS_CUR + i] = acc;
            ws[WS_BLK + i] = bacc;
            int c = ws[WS_CNT + i];
            acc += c;
            bacc += (c + BM - 1) / BM;
        }
        ws[WS_OFF + NDIR] = acc;
        ws[WS_BLK + NDIR] = bacc;
    }
}

__global__ void scatter_kernel(const int* __restrict__ vec, const int* __restrict__ dmap,
                               int* __restrict__ ws) {
    __shared__ int h[NDIR];
    __shared__ int base[NDIR];
    int t = threadIdx.x;
    if (t < NDIR) h[t] = 0;
    __syncthreads();
    int id = blockIdx.x * 256 + t;
    int d = 0, pos = 0;
    if (id < TOTAL) {
        d = dmap[vec[id]];
        pos = atomicAdd(&h[d], 1);
    }
    __syncthreads();
    if (t < NDIR) base[t] = h[t] ? atomicAdd(&ws[WS_CUR + t], h[t]) : 0;
    __syncthreads();
    if (id < TOTAL) ws[WS_IDS + base[d] + pos] = id;
}

// Pre-transpose + bf16-split + swizzle W into d_ws (R7 layout; 0 conflicts).
// Per (dir d, kstep s): 16KB = hi[col][chunk'][i] (8KB) then lo (8KB);
// stored chunk c' holds source chunk c'^key, key(col) = (col>>1)&3.
__global__ void wconvert_kernel(const float* __restrict__ W, int* __restrict__ ws) {
    unsigned short* wt = (unsigned short*)(ws + WS_WT);
    int g = blockIdx.x * 256 + threadIdx.x;      // 0..196607
    int dsb = g >> 12;                           // d*8+s, 0..47
    int e = g & 4095;
    int col = e >> 5;
    int kk = e & 31;
    int cp = kk >> 3, i = kk & 7;
    int key = (col >> 1) & 3;
    int d = dsb >> 3, s = dsb & 7;
    int ksrc = s * 32 + ((cp ^ key) << 3) + i;
    float w = W[((d * 256) + ksrc) * 128 + col];
    unsigned u = __float_as_uint(w);
    float hf = __uint_as_float(u & 0xFFFF0000u);
    float lf = w - hf;
    int base = dsb * 8192 + col * 32 + cp * 8 + i;
    wt[base] = (unsigned short)(u >> 16);
    wt[base + 4096] = (unsigned short)(__float_as_uint(lf) >> 16);
}

__device__ __forceinline__ void cvt8(float4 a, float4 b, s16x8& h, s16x8& lo) {
    float x[8] = {a.x, a.y, a.z, a.w, b.x, b.y, b.z, b.w};
    #pragma unroll
    for (int j = 0; j < 8; ++j) {
        unsigned u = __float_as_uint(x[j]);
        float hf = __uint_as_float(u & 0xFFFF0000u);
        float lf = x[j] - hf;
        h[j] = (short)(u >> 16);
        lo[j] = (short)(__float_as_uint(lf) >> 16);
    }
}

#define CFENCE() asm volatile("" ::: "memory")

// MFMA gather-GEMM with counted-vmcnt pipeline (no vmcnt(0) drain in loop):
// per iter t: [issue STAGE_{t+1}] [vmcnt(8): A_t,S_t done] [s_barrier #1]
// [cvt A_t] [issue A_{t+2}] [ds_read + 48 MFMA] [s_barrier #2].
// Queue (oldest->newest) entering t: A_t, S_t, A_{t+1}; after S-issue: +S_{t+1}
// -> vmcnt(8) leaves {A_{t+1}, S_{t+1}}. A gets ~2 iters of latency coverage.
// Best-measured variant of the session (76.2 us, R10). Terminal reversion:
// six structural variants (drain-barrier / B-from-L2 / counted-vmcnt /
// 2x-occupancy / whole-row-burst / locality-sort) all land 76-84 us with
// ~140 MB invariant HBM traffic at ~1.7-1.85 TB/s scattered-service rate.
__global__ __launch_bounds__(256, 3) void gemm_kernel(
    const float* __restrict__ last, const float* __restrict__ bias,
    const float* __restrict__ alphap,
    const int* __restrict__ vec, const int* __restrict__ drev,
    const int* __restrict__ child_l, const int* __restrict__ child_r,
    const int* __restrict__ ws, float* __restrict__ out)
{
    int i = blockIdx.x;
    if (i >= ws[WS_BLK + NDIR]) return;
    int dir = 0;
    #pragma unroll
    for (int d = 1; d < NDIR; ++d)
        if (i >= ws[WS_BLK + d]) dir = d;
    int tile = i - ws[WS_BLK + dir];
    int start = ws[WS_OFF + dir];
    int end   = ws[WS_OFF + dir + 1];
    int m0 = start + tile * BM;
    const int* ids = ws + WS_IDS;

    __shared__ unsigned short wbuf[2][8192];   // 2 x 16KB W tiles
    __shared__ int s_row0[BM], s_row1[BM], s_oid[BM];

    int t = threadIdx.x;
    int l = t & 63;
    int wid = t >> 6;

    if (t < BM) {
        int idx = m0 + t;
        bool valid = idx < end;
        int id = ids[valid ? idx : end - 1];
        int b = id >> 13;            // N_OUT = 8192
        int n = id & (N_OUT - 1);
        int v = vec[id];
        int r = drev[v];
        int cl = child_l[n];
        int cr = child_r[n];
        int first  = r ? cr : cl;
        int second = r ? cl : cr;
        s_row0[t] = b * N_IN + first;
        s_row1[t] = b * N_IN + second;
        s_oid[t]  = valid ? id : -1;
    }
    __syncthreads();   // once, before the pipeline starts

    // hoist row indices into registers
    int rowA[2][2];
    #pragma unroll
    for (int f = 0; f < 2; ++f) {
        int m = wid * 32 + f * 16 + (l & 15);
        rowA[0][f] = s_row0[m];
        rowA[1][f] = s_row1[m];
    }

    const char* wt_blk = (const char*)(ws + WS_WT) + (size_t)dir * 8 * 16384;

    #define STAGE_W(buf, s_)                                                     \
        {                                                                        \
            const char* gsrc = wt_blk + (size_t)(s_) * 16384 + wid * 4096 + l * 16; \
            char* ldst = (char*)&wbuf[buf][0] + wid * 4096;                      \
            _Pragma("unroll")                                                    \
            for (int i_ = 0; i_ < 4; ++i_) {                                     \
                __builtin_amdgcn_global_load_lds(                                \
                    (const __attribute__((address_space(1))) void*)(gsrc + i_ * 1024), \
                    (__attribute__((address_space(3))) void*)(ldst + i_ * 1024), \
                    16, 0, 0);                                                   \
            }                                                                    \
        }

    #define ISSUE_A(buf, s_)                                                     \
        {                                                                        \
            _Pragma("unroll")                                                    \
            for (int f_ = 0; f_ < 2; ++f_) {                                     \
                const float* src = last + (size_t)rowA[(s_) >> 2][f_] * IDIM     \
                                 + ((s_) & 3) * 32 + (l >> 4) * 8;               \
                xa0[buf][f_] = *(const float4*)src;                              \
                xa1[buf][f_] = *(const float4*)(src + 4);                        \
            }                                                                    \
        }

    f32x4 acc[2][8];
    #pragma unroll
    for (int f = 0; f < 2; ++f)
        #pragma unroll
        for (int nf = 0; nf < 8; ++nf)
            acc[f][nf] = (f32x4){0.f, 0.f, 0.f, 0.f};

    float4 xa0[2][2], xa1[2][2];   // 2-deep A ring (all indices static)

    // prologue: queue = [S0, A0, A1]
    STAGE_W(0, 0);
    CFENCE();
    ISSUE_A(0, 0);
    ISSUE_A(1, 1);
    CFENCE();

    #pragma unroll
    for (int s = 0; s < 8; ++s) {
        int cur = s & 1;
        // --- issue STAGE_{s+1} (buffer protected by barrier #2 of iter s-1)
        if (s < 7) { STAGE_W(cur ^ 1, s + 1); CFENCE(); }
        // --- counted wait: A_s and S_s complete; later loads stay in flight
        if (s < 7) { asm volatile("s_waitcnt vmcnt(8)" ::: "memory"); }
        else       { asm volatile("s_waitcnt vmcnt(0)" ::: "memory"); }
        __builtin_amdgcn_s_barrier();   // #1: buf[cur] staged by ALL waves
        CFENCE();
        // --- consume A_s
        s16x8 ah[2], al[2];
        #pragma unroll
        for (int f = 0; f < 2; ++f) cvt8(xa0[cur][f], xa1[cur][f], ah[f], al[f]);
        // --- issue A_{s+2} into the ring slot just freed
        if (s < 6) { CFENCE(); ISSUE_A(cur, s + 2); CFENCE(); }
        // --- B frags in quarters + 3-term split MFMA
        #pragma unroll
        for (int q = 0; q < 4; ++q) {
            s16x8 bh[2], bl[2];
            #pragma unroll
            for (int i2 = 0; i2 < 2; ++i2) {
                int nf = q * 2 + i2;
                int col = nf * 16 + (l & 15);
                int cp = (l >> 4) ^ ((col >> 1) & 3);
                int off = col * 32 + cp * 8;          // shorts
                bh[i2] = *(const s16x8*)&wbuf[cur][off];
                bl[i2] = *(const s16x8*)&wbuf[cur][off + 4096];
            }
            #pragma unroll
            for (int f = 0; f < 2; ++f) {
                #pragma unroll
                for (int i2 = 0; i2 < 2; ++i2) {
                    int nf = q * 2 + i2;
                    acc[f][nf] = __builtin_amdgcn_mfma_f32_16x16x32_bf16(ah[f], bh[i2], acc[f][nf], 0, 0, 0);
                    acc[f][nf] = __builtin_amdgcn_mfma_f32_16x16x32_bf16(ah[f], bl[i2], acc[f][nf], 0, 0, 0);
                    acc[f][nf] = __builtin_amdgcn_mfma_f32_16x16x32_bf16(al[f], bh[i2], acc[f][nf], 0, 0, 0);
                }
            }
        }
        // --- #2: all waves done reading buf[cur]; next iter may stage into it
        if (s < 7) {
            CFENCE();
            __builtin_amdgcn_s_barrier();
            CFENCE();
        }
    }

    // --- epilogue: D frag row=(l>>4)*4+j, col=l&15 (m89/m91 verified)
    float alpha = alphap[0];
    #pragma unroll
    for (int nf = 0; nf < 8; ++nf) {
        int col = nf * 16 + (l & 15);
        float bv = bias[dir * ODIM + col];
        #pragma unroll
        for (int f = 0; f < 2; ++f) {
            #pragma unroll
            for (int j = 0; j < 4; ++j) {
                int mloc = wid * 32 + f * 16 + (l >> 4) * 4 + j;
                int id = s_oid[mloc];
                if (id < 0) continue;
                float y = acc[f][nf][j] + bv;
                out[(size_t)id * ODIM + col] = y >= 0.f ? y : alpha * y;
            }
        }
    }
    #undef STAGE_W
    #undef ISSUE_A
}

extern "C" void kernel_launch(void* const* d_in, const int* in_sizes, int n_in,
                              void* d_out, int out_size, void* d_ws, size_t ws_size,
                              hipStream_t stream) {
    const float* last    = (const float*)d_in[0];
    const float* W       = (const float*)d_in[1];
    const float* bias    = (const float*)d_in[2];
    const float* alpha   = (const float*)d_in[3];
    const int*   vec     = (const int*)d_in[4];
    const int*   dmap    = (const int*)d_in[5];
    const int*   drev    = (const int*)d_in[6];
    const int*   child_l = (const int*)d_in[7];
    const int*   child_r = (const int*)d_in[8];
    float* out = (float*)d_out;
    int*   ws  = (int*)d_ws;

    zero_kernel<<<1, 64, 0, stream>>>(ws);
    count_kernel<<<TOTAL / 256, 256, 0, stream>>>(vec, dmap, ws);
    prefix_kernel<<<1, 64, 0, stream>>>(ws);
    scatter_kernel<<<TOTAL / 256, 256, 0, stream>>>(vec, dmap, ws);
    wconvert_kernel<<<(NDIR * 8 * 4096) / 256, 256, 0, stream>>>(W, ws);
    gemm_kernel<<<MAXBLK, 256, 0, stream>>>(last, bias, alpha, vec, drev,
                                            child_l, child_r, ws, out);
}